// Round 1
// baseline (825.180 us; speedup 1.0000x reference)
//
#include <hip/hip_runtime.h>
#include <hip/hip_bf16.h>
#include <math.h>

#define BB 8
#define TT 1024
#define CC 64
#define HH 8
#define DH 8
#define NLAY 4
#define VV 32000
#define FF 256
#define NR (BB*TT)                 // 8192
#define NLOGIT 262144000           // NR*VV, fits int32
#define NCB 125                    // 32000/256 col-chunks

typedef unsigned short u16;
typedef __attribute__((ext_vector_type(8))) short short8v;
typedef __attribute__((ext_vector_type(4))) float f32x4;

__device__ __forceinline__ float b2f(u16 u){
  union { float f; unsigned int i; } c; c.i = ((unsigned int)u) << 16; return c.f;
}
__device__ __forceinline__ u16 f2b(float f){
  union { float f; unsigned int i; } c; c.f = f;
  unsigned int x = c.i;
  return (u16)((x + 0x7FFF + ((x >> 16) & 1)) >> 16);
}

// ---------------- dtype probe: ln1_g ~ N(1, 0.02) ----------------
__global__ void k_probe(const void* ln1g, int* flag){
  if (threadIdx.x == 0 && blockIdx.x == 0){
    const u16* p = (const u16*)ln1g;
    int cnt = 0;
    for (int i = 0; i < 256; i++){ if ((p[i] >> 8) == 0x3F) cnt++; }
    *flag = (cnt > 192) ? 1 : 0;   // bf16 -> ~256 hits, f32 -> ~128
  }
}

// ---------------- convert all float inputs -> f32 ws (+ Wout -> bf16) ----------------
struct ConvArgs {
  const void* src[18];
  float* dst[18];
  int n[18];
  int blkoff[19];
  const int* flag;
  u16* wout16;
};
__global__ void k_convert(ConvArgs a){
  int isb = *a.flag;
  int bid = blockIdx.x;
  int t = 0;
  while (bid >= a.blkoff[t + 1]) t++;
  int base = (bid - a.blkoff[t]) * 1024 + threadIdx.x;
  const u16* s16 = (const u16*)a.src[t];
  const float* s32 = (const float*)a.src[t];
  float* d = a.dst[t];
  int n = a.n[t];
  #pragma unroll
  for (int e = 0; e < 4; e++){
    int i = base + e * 256;
    if (i < n){
      float v = isb ? b2f(s16[i]) : s32[i];
      d[i] = v;
      if (t == 16) a.wout16[i] = f2b(v);
    }
  }
}

// ---------------- embedding ----------------
__global__ void k_embed(const int* __restrict__ x, const float* __restrict__ tok,
                        const float* __restrict__ pos, float* __restrict__ h){
  int i = blockIdx.x * 256 + threadIdx.x;      // 524288 total
  int r = i >> 6, c = i & 63;
  int t = r & (TT - 1);
  h[i] = tok[x[r] * 64 + c] + pos[t * 64 + c];
}

// ---------------- qkv projection (k stored pre-permuted per the reference's reshape) ----------------
__global__ void k_qkv(const float* __restrict__ h,
                      const float* __restrict__ wq, const float* __restrict__ bq,
                      const float* __restrict__ wk, const float* __restrict__ bk,
                      const float* __restrict__ wv, const float* __restrict__ bv,
                      float* __restrict__ q, float* __restrict__ kp, float* __restrict__ vv){
  __shared__ float hs[4][64];
  int tid = threadIdx.x;
  int row0 = blockIdx.x * 4;
  hs[tid >> 6][tid & 63] = h[row0 * 64 + tid];
  __syncthreads();
  int rr = tid >> 6, o = tid & 63;
  int head = o >> 3, d = o & 7;
  int row = row0 + rr;
  int b = row >> 10, t = row & (TT - 1);
  float aq = bq[head * 8 + d], ak = bk[head * 8 + d], av = bv[head * 8 + d];
  #pragma unroll
  for (int c = 0; c < 64; c++){
    float hv = hs[rr][c];
    aq += hv * wq[(head * 64 + c) * 8 + d];
    ak += hv * wk[(head * 64 + c) * 8 + d];
    av += hv * wv[(head * 64 + c) * 8 + d];
  }
  int bh = b * HH + head;
  q[(bh * TT + t) * 8 + d] = aq;
  int i = t * 8 + d;                        // flat index in k's [T,D]
  kp[(bh * TT + (i & 1023)) * 8 + (i >> 10)] = ak;   // kp[s][d2] = kr[d2][s]
  vv[(bh * TT + t) * 8 + d] = av;
}

// ---------------- fused causal attention (flash-style) ----------------
__global__ void k_attn(const float* __restrict__ q, const float* __restrict__ kp,
                       const float* __restrict__ vv, float* __restrict__ att){
  __shared__ float qs[64][8], ks[64][8], vs[64][8];
  __shared__ float2 ml[256];
  __shared__ float po[256][8];
  int tid = threadIdx.x;
  int bh = blockIdx.y;
  int t0 = blockIdx.x * 64;
  const float* qb = q + (bh * TT + t0) * 8;
  for (int idx = tid; idx < 512; idx += 256) ((float*)qs)[idx] = qb[idx];
  __syncthreads();
  int tr = tid >> 2, pp = tid & 3;
  int t = t0 + tr;
  float qr[8];
  #pragma unroll
  for (int d = 0; d < 8; d++) qr[d] = qs[tr][d];
  float m = -1e30f, l = 0.f;
  float o[8] = {0,0,0,0,0,0,0,0};
  int ntile = blockIdx.x + 1;
  for (int st = 0; st < ntile; st++){
    int s0 = st * 64;
    __syncthreads();
    const float* kb = kp + (bh * TT + s0) * 8;
    const float* vb = vv + (bh * TT + s0) * 8;
    for (int idx = tid; idx < 512; idx += 256){
      ((float*)ks)[idx] = kb[idx];
      ((float*)vs)[idx] = vb[idx];
    }
    __syncthreads();
    float sc[16];
    float tm = -1e30f;
    #pragma unroll
    for (int j = 0; j < 16; j++){
      int si = pp + j * 4;
      int s = s0 + si;
      float acc = 0.f;
      #pragma unroll
      for (int d = 0; d < 8; d++) acc += qr[d] * ks[si][d];
      sc[j] = (s <= t) ? acc * 0.35355339059327378f : -1e30f;
      tm = fmaxf(tm, sc[j]);
    }
    float mn = fmaxf(m, tm);
    float fac = __expf(m - mn);            // 0 if m=-1e30 & mn finite; 1 if both sentinel
    l *= fac;
    #pragma unroll
    for (int d = 0; d < 8; d++) o[d] *= fac;
    #pragma unroll
    for (int j = 0; j < 16; j++){
      if (sc[j] > -0.9e30f){
        float e = __expf(sc[j] - mn);
        l += e;
        int si = pp + j * 4;
        #pragma unroll
        for (int d = 0; d < 8; d++) o[d] += e * vs[si][d];
      }
    }
    m = mn;
  }
  ml[tid] = make_float2(m, l);
  #pragma unroll
  for (int d = 0; d < 8; d++) po[tid][d] = o[d];
  __syncthreads();
  if (pp == 0){
    float M = -1e30f;
    #pragma unroll
    for (int p2 = 0; p2 < 4; p2++) M = fmaxf(M, ml[tid + p2].x);
    float L = 0.f;
    float O[8] = {0,0,0,0,0,0,0,0};
    #pragma unroll
    for (int p2 = 0; p2 < 4; p2++){
      float w = __expf(ml[tid + p2].x - M);
      L += ml[tid + p2].y * w;
      #pragma unroll
      for (int d = 0; d < 8; d++) O[d] += po[tid + p2][d] * w;
    }
    float inv = 1.f / L;
    int b = bh >> 3, hh = bh & 7;
    float* op = att + (b * TT + t) * 64 + hh * 8;
    #pragma unroll
    for (int d = 0; d < 8; d++) op[d] = O[d] * inv;
  }
}

// ---------------- h += LN(attn_out) ----------------
__global__ void k_lnres(const float* __restrict__ src, const float* __restrict__ g,
                        const float* __restrict__ bb, float* __restrict__ h){
  int tid = threadIdx.x;
  int row = blockIdx.x * 4 + (tid >> 6);
  int lane = tid & 63;
  float x = src[row * 64 + lane];
  float s = x, sq = x * x;
  for (int msk = 32; msk; msk >>= 1){
    s += __shfl_xor(s, msk, 64);
    sq += __shfl_xor(sq, msk, 64);
  }
  float mu = s * (1.f / 64);
  float var = sq * (1.f / 64) - mu * mu;
  float rstd = rsqrtf(fmaxf(var, 0.f) + 1e-5f);
  h[row * 64 + lane] += (x - mu) * rstd * g[lane] + bb[lane];
}

// ---------------- h += relu(LN2(h)@W1+b1)@W2 + b2 ----------------
__global__ void k_ffn(float* __restrict__ h, const float* __restrict__ g, const float* __restrict__ bb,
                      const float* __restrict__ w1, const float* __restrict__ b1,
                      const float* __restrict__ w2, const float* __restrict__ b2){
  __shared__ float z[8][64];
  __shared__ float a[8][256];
  int tid = threadIdx.x;
  int row0 = blockIdx.x * 8;
  {
    int rr = tid >> 5, cp = tid & 31;
    int c0 = cp * 2;
    const float* hp = h + (row0 + rr) * 64;
    float x0 = hp[c0], x1 = hp[c0 + 1];
    float s = x0 + x1, sq = x0 * x0 + x1 * x1;
    for (int msk = 16; msk; msk >>= 1){
      s += __shfl_xor(s, msk, 64);
      sq += __shfl_xor(sq, msk, 64);
    }
    float mu = s * (1.f / 64);
    float var = sq * (1.f / 64) - mu * mu;
    float rstd = rsqrtf(fmaxf(var, 0.f) + 1e-5f);
    z[rr][c0]     = (x0 - mu) * rstd * g[c0] + bb[c0];
    z[rr][c0 + 1] = (x1 - mu) * rstd * g[c0 + 1] + bb[c0 + 1];
  }
  __syncthreads();
  {
    int j = tid;
    float acc[8];
    float bj = b1[j];
    #pragma unroll
    for (int r = 0; r < 8; r++) acc[r] = bj;
    for (int c = 0; c < 64; c++){
      float w = w1[c * 256 + j];
      #pragma unroll
      for (int r = 0; r < 8; r++) acc[r] += z[r][c] * w;
    }
    #pragma unroll
    for (int r = 0; r < 8; r++) a[r][j] = fmaxf(acc[r], 0.f);
  }
  __syncthreads();
  #pragma unroll
  for (int half = 0; half < 2; half++){
    int oi = tid + half * 256;
    int r = oi >> 6, c = oi & 63;
    float acc = b2[c];
    for (int k = 0; k < 256; k++) acc += a[r][k] * w2[k * 64 + c];
    h[(row0 + r) * 64 + c] += acc;
  }
}

// ---------------- h -> bf16 ----------------
__global__ void k_h2b(const float* __restrict__ h, u16* __restrict__ hb){
  int i = blockIdx.x * 256 + threadIdx.x;
  hb[i] = f2b(h[i]);
}

// ---------------- logits = hb @ Wout + bout (MFMA), fused softmax partials ----------------
__global__ void __launch_bounds__(256) k_logits(const u16* __restrict__ hb, const u16* __restrict__ wb,
                                                const float* __restrict__ bout, float* __restrict__ logits,
                                                float2* __restrict__ part){
  int tid = threadIdx.x;
  int wave = tid >> 6, lane = tid & 63;
  int lr = lane & 15, lg = lane >> 4;
  int row0 = blockIdx.y * 64;
  int colw = blockIdx.x * 256 + wave * 64;

  short8v af[4][2];
  #pragma unroll
  for (int mi = 0; mi < 4; mi++)
    #pragma unroll
    for (int kk = 0; kk < 2; kk++)
      af[mi][kk] = *(const short8v*)(hb + (row0 + mi * 16 + lr) * 64 + kk * 32 + lg * 8);

  short8v bf[4][2];
  #pragma unroll
  for (int nf = 0; nf < 4; nf++){
    int col = colw + nf * 16 + lr;
    #pragma unroll
    for (int kk = 0; kk < 2; kk++){
      #pragma unroll
      for (int i = 0; i < 8; i++)
        bf[nf][kk][i] = (short)wb[(kk * 32 + lg * 8 + i) * VV + col];
    }
  }

  f32x4 acc[4][4];
  #pragma unroll
  for (int mi = 0; mi < 4; mi++)
    #pragma unroll
    for (int nf = 0; nf < 4; nf++)
      acc[mi][nf] = (f32x4){0.f, 0.f, 0.f, 0.f};

  #pragma unroll
  for (int mi = 0; mi < 4; mi++){
    #pragma unroll
    for (int nf = 0; nf < 4; nf++){
      acc[mi][nf] = __builtin_amdgcn_mfma_f32_16x16x32_bf16(af[mi][0], bf[nf][0], acc[mi][nf], 0, 0, 0);
      acc[mi][nf] = __builtin_amdgcn_mfma_f32_16x16x32_bf16(af[mi][1], bf[nf][1], acc[mi][nf], 0, 0, 0);
    }
  }

  float bo[4];
  #pragma unroll
  for (int nf = 0; nf < 4; nf++) bo[nf] = bout[colw + nf * 16 + lr];

  // write logits: D[row = 4*lg + r (+16*mi)][col = lr (+16*nf)]
  #pragma unroll
  for (int mi = 0; mi < 4; mi++){
    #pragma unroll
    for (int nf = 0; nf < 4; nf++){
      int colg = colw + nf * 16 + lr;
      #pragma unroll
      for (int r = 0; r < 4; r++){
        int rowg = row0 + mi * 16 + lg * 4 + r;
        logits[(size_t)rowg * VV + colg] = acc[mi][nf][r] + bo[nf];
      }
    }
  }

  // per-row (m, sumexp) over this wave's 64 cols
  __shared__ float2 wml[4][64];
  #pragma unroll
  for (int mi = 0; mi < 4; mi++){
    #pragma unroll
    for (int r = 0; r < 4; r++){
      float v0 = acc[mi][0][r] + bo[0], v1 = acc[mi][1][r] + bo[1];
      float v2 = acc[mi][2][r] + bo[2], v3 = acc[mi][3][r] + bo[3];
      float mx = fmaxf(fmaxf(v0, v1), fmaxf(v2, v3));
      for (int msk = 1; msk < 16; msk <<= 1) mx = fmaxf(mx, __shfl_xor(mx, msk, 64));
      float sume = __expf(v0 - mx) + __expf(v1 - mx) + __expf(v2 - mx) + __expf(v3 - mx);
      for (int msk = 1; msk < 16; msk <<= 1) sume += __shfl_xor(sume, msk, 64);
      if (lr == 0) wml[wave][mi * 16 + lg * 4 + r] = make_float2(mx, sume);
    }
  }
  __syncthreads();
  if (tid < 64){
    float M = -1e30f;
    #pragma unroll
    for (int w = 0; w < 4; w++) M = fmaxf(M, wml[w][tid].x);
    float L = 0.f;
    #pragma unroll
    for (int w = 0; w < 4; w++){
      float2 p = wml[w][tid];
      L += p.y * __expf(p.x - M);
    }
    part[(size_t)blockIdx.x * NR + row0 + tid] = make_float2(M, L);
  }
}

// ---------------- loss reduction ----------------
__global__ void k_loss(const float2* __restrict__ part, const float* __restrict__ logits,
                       const int* __restrict__ tgt, float* __restrict__ lpart){
  int row = blockIdx.x * 256 + threadIdx.x;
  float M = -1e30f;
  for (int j = 0; j < NCB; j++) M = fmaxf(M, part[(size_t)j * NR + row].x);
  float L = 0.f;
  for (int j = 0; j < NCB; j++){
    float2 p = part[(size_t)j * NR + row];
    L += p.y * __expf(p.x - M);
  }
  float lse = M + __logf(L);
  float tl = logits[(size_t)row * VV + tgt[row]];
  float nll = lse - tl;
  __shared__ float red[4];
  for (int msk = 32; msk; msk >>= 1) nll += __shfl_xor(nll, msk, 64);
  if ((threadIdx.x & 63) == 0) red[threadIdx.x >> 6] = nll;
  __syncthreads();
  if (threadIdx.x == 0) lpart[blockIdx.x] = red[0] + red[1] + red[2] + red[3];
}
__global__ void k_loss2(const float* __restrict__ lpart, float* __restrict__ out){
  if (threadIdx.x == 0 && blockIdx.x == 0){
    float s = 0.f;
    for (int i = 0; i < 32; i++) s += lpart[i];
    out[NLOGIT] = s * (1.f / NR);
  }
}

extern "C" void kernel_launch(void* const* d_in, const int* in_sizes, int n_in,
                              void* d_out, int out_size, void* d_ws, size_t ws_size,
                              hipStream_t stream){
  (void)in_sizes; (void)n_in; (void)out_size; (void)ws_size;
  const int* x = (const int*)d_in[0];
  const int* targets = (const int*)d_in[1];
  float* out = (float*)d_out;

  static const int WN[18] = {2048000, 65536, 16384, 256, 16384, 256, 16384, 256,
                             256, 256, 256, 256, 65536, 1024, 65536, 256, 2048000, 32000};
  char* ws = (char*)d_ws;
  size_t off = 0;
  auto alloc = [&](size_t bytes) -> void* {
    void* p = ws + off;
    off += (bytes + 255) & ~(size_t)255;
    return p;
  };
  int* flag = (int*)alloc(256);
  float* wf[18];
  for (int i = 0; i < 18; i++) wf[i] = (float*)alloc((size_t)WN[i] * 4);
  float* h     = (float*)alloc((size_t)NR * 64 * 4);
  float* q     = (float*)alloc((size_t)NR * 64 * 4);
  float* kp    = (float*)alloc((size_t)NR * 64 * 4);
  float* v     = (float*)alloc((size_t)NR * 64 * 4);
  float* att_o = (float*)alloc((size_t)NR * 64 * 4);
  u16* hb      = (u16*)alloc((size_t)NR * 64 * 2);
  u16* wout16  = (u16*)alloc((size_t)2048000 * 2);
  float2* part = (float2*)alloc((size_t)NCB * NR * 8);
  float* lpart = (float*)alloc(32 * 4);

  // probe dtype, convert weights
  hipLaunchKernelGGL(k_probe, dim3(1), dim3(64), 0, stream, d_in[10], flag);
  ConvArgs ca;
  int blk = 0;
  for (int i = 0; i < 18; i++){
    ca.src[i] = d_in[2 + i];
    ca.dst[i] = wf[i];
    ca.n[i] = WN[i];
    ca.blkoff[i] = blk;
    blk += (WN[i] + 1023) / 1024;
  }
  ca.blkoff[18] = blk;
  ca.flag = flag;
  ca.wout16 = wout16;
  hipLaunchKernelGGL(k_convert, dim3(blk), dim3(256), 0, stream, ca);

  hipLaunchKernelGGL(k_embed, dim3(2048), dim3(256), 0, stream, x, wf[0], wf[1], h);

  for (int l = 0; l < NLAY; l++){
    hipLaunchKernelGGL(k_qkv, dim3(2048), dim3(256), 0, stream, h,
                       wf[2] + l * 4096, wf[3] + l * 64,
                       wf[4] + l * 4096, wf[5] + l * 64,
                       wf[6] + l * 4096, wf[7] + l * 64,
                       q, kp, v);
    hipLaunchKernelGGL(k_attn, dim3(16, 64), dim3(256), 0, stream, q, kp, v, att_o);
    hipLaunchKernelGGL(k_lnres, dim3(2048), dim3(256), 0, stream, att_o,
                       wf[8] + l * 64, wf[9] + l * 64, h);
    hipLaunchKernelGGL(k_ffn, dim3(1024), dim3(256), 0, stream, h,
                       wf[10] + l * 64, wf[11] + l * 64,
                       wf[12] + l * 16384, wf[13] + l * 256,
                       wf[14] + l * 16384, wf[15] + l * 64);
  }

  hipLaunchKernelGGL(k_h2b, dim3(2048), dim3(256), 0, stream, h, hb);
  hipLaunchKernelGGL(k_logits, dim3(NCB, 128), dim3(256), 0, stream, hb, wout16, wf[17], out, part);
  hipLaunchKernelGGL(k_loss, dim3(32), dim3(256), 0, stream, part, out, targets, lpart);
  hipLaunchKernelGGL(k_loss2, dim3(1), dim3(64), 0, stream, lpart, out);
}

// Round 2
// 792.044 us; speedup vs baseline: 1.0418x; 1.0418x over previous
//
#include <hip/hip_runtime.h>
#include <hip/hip_bf16.h>
#include <math.h>

#define BB 8
#define TT 1024
#define CC 64
#define HH 8
#define DH 8
#define NLAY 4
#define VV 32000
#define FF 256
#define NR (BB*TT)                 // 8192
#define NLOGIT 262144000           // NR*VV
#define NCB 125                    // 32000/256 col-chunks

typedef unsigned short u16;
typedef unsigned int u32;
typedef __attribute__((ext_vector_type(8))) short short8v;
typedef __attribute__((ext_vector_type(4))) float f32x4;

__device__ __forceinline__ float b2f(u16 u){
  union { float f; u32 i; } c; c.i = ((u32)u) << 16; return c.f;
}
__device__ __forceinline__ u16 f2b(float f){
  union { float f; u32 i; } c; c.f = f;
  u32 x = c.i;
  return (u16)((x + 0x7FFF + ((x >> 16) & 1)) >> 16);
}
__device__ __forceinline__ u32 pack2(float lo, float hi){
  return (u32)f2b(lo) | ((u32)f2b(hi) << 16);
}

// ---------------- dtype probe: ln1_g ~ N(1, 0.02) ----------------
__global__ void k_probe(const void* ln1g, int* flag){
  if (threadIdx.x == 0 && blockIdx.x == 0){
    const u16* p = (const u16*)ln1g;
    int cnt = 0;
    for (int i = 0; i < 256; i++){ if ((p[i] >> 8) == 0x3F) cnt++; }
    *flag = (cnt > 192) ? 1 : 0;   // bf16 -> ~256 hits, f32 -> ~128
  }
}

// ---------------- convert float inputs -> f32 ws (+ Wout -> transposed bf16) ----------------
struct ConvArgs {
  const void* src[18];
  float* dst[18];
  int n[18];
  int blkoff[19];
  const int* flag;
  u16* wt16;           // Wout^T bf16 [32000][64]
};
__global__ void k_convert(ConvArgs a){
  int isb = *a.flag;
  int bid = blockIdx.x;
  int t = 0;
  while (bid >= a.blkoff[t + 1]) t++;
  int base = (bid - a.blkoff[t]) * 1024 + threadIdx.x;
  const u16* s16 = (const u16*)a.src[t];
  const float* s32 = (const float*)a.src[t];
  float* d = a.dst[t];
  int n = a.n[t];
  #pragma unroll
  for (int e = 0; e < 4; e++){
    int i = base + e * 256;
    if (i < n){
      float v = isb ? b2f(s16[i]) : s32[i];
      d[i] = v;
      if (t == 16){
        int k = i / VV, col = i - k * VV;
        a.wt16[(size_t)col * 64 + k] = f2b(v);
      }
    }
  }
}

// ---------------- embedding ----------------
__global__ void k_embed(const int* __restrict__ x, const float* __restrict__ tok,
                        const float* __restrict__ pos, float* __restrict__ h){
  int i = blockIdx.x * 256 + threadIdx.x;
  int r = i >> 6, c = i & 63;
  int t = r & (TT - 1);
  h[i] = tok[x[r] * 64 + c] + pos[t * 64 + c];
}

// ---------------- qkv projection -> bf16 (q scaled, k permuted, v transposed) ----------------
__global__ void k_qkv(const float* __restrict__ h,
                      const float* __restrict__ wq, const float* __restrict__ bq,
                      const float* __restrict__ wk, const float* __restrict__ bk,
                      const float* __restrict__ wv, const float* __restrict__ bv,
                      u16* __restrict__ q16, u16* __restrict__ kp16, u16* __restrict__ vt16){
  __shared__ float hs[4][64];
  int tid = threadIdx.x;
  int row0 = blockIdx.x * 4;
  hs[tid >> 6][tid & 63] = h[row0 * 64 + tid];
  __syncthreads();
  int rr = tid >> 6, o = tid & 63;
  int head = o >> 3, d = o & 7;
  int row = row0 + rr;
  int b = row >> 10, t = row & (TT - 1);
  float aq = bq[head * 8 + d], ak = bk[head * 8 + d], av = bv[head * 8 + d];
  #pragma unroll
  for (int c = 0; c < 64; c++){
    float hv = hs[rr][c];
    aq += hv * wq[(head * 64 + c) * 8 + d];
    ak += hv * wk[(head * 64 + c) * 8 + d];
    av += hv * wv[(head * 64 + c) * 8 + d];
  }
  int bh = b * HH + head;
  q16[((size_t)bh * TT + t) * 8 + d] = f2b(aq * 0.35355339059327378f);  // fold 1/sqrt(8)
  int i = t * 8 + d;                                  // faithful reshape(B,H,D,T)
  kp16[((size_t)bh * TT + (i & 1023)) * 8 + (i >> 10)] = f2b(ak);
  vt16[((size_t)bh * 8 + d) * TT + t] = f2b(av);
}

// ---------------- MFMA causal attention, one wave per 16-row q-tile ----------------
__global__ void __launch_bounds__(64) k_attn(const u16* __restrict__ q16, const u16* __restrict__ kp16,
                                             const u16* __restrict__ vt16, float* __restrict__ att){
  int lane = threadIdx.x & 63;
  int lr = lane & 15, lg = lane >> 4;
  int bh = blockIdx.y;
  int tb = blockIdx.x * 16;          // 64 tiles per bh
  int t_g = tb + lr;

  // Q fragment (B-operand): lane holds B[k=lg*8+i][col=t=lr]; only k<8 real
  short8v qf = {0,0,0,0,0,0,0,0};
  if (lg == 0) qf = *(const short8v*)(q16 + ((size_t)bh * TT + tb + lr) * 8);

  float m = -1e30f, l = 0.f;
  f32x4 o = {0.f, 0.f, 0.f, 0.f};
  int nchunk = (tb >> 5) + 1;

  for (int c = 0; c < nchunk; c++){
    int s0 = c * 32;
    bool skipB = (s0 + 16 > tb + 15);
    short8v kA = {0,0,0,0,0,0,0,0}, kB = {0,0,0,0,0,0,0,0};
    if (lg == 0){
      kA = *(const short8v*)(kp16 + ((size_t)bh * TT + s0 + lr) * 8);
      if (!skipB) kB = *(const short8v*)(kp16 + ((size_t)bh * TT + s0 + 16 + lr) * 8);
    }
    // S^T frags: D[row=s_local=lg*4+r][col=t=lr]
    f32x4 sA = __builtin_amdgcn_mfma_f32_16x16x32_bf16(kA, qf, (f32x4){0.f,0.f,0.f,0.f}, 0, 0, 0);
    f32x4 sB;
    if (!skipB)
      sB = __builtin_amdgcn_mfma_f32_16x16x32_bf16(kB, qf, (f32x4){0.f,0.f,0.f,0.f}, 0, 0, 0);
    else
      sB = (f32x4){-1e30f, -1e30f, -1e30f, -1e30f};

    if (s0 + 15 > tb){                       // tileA touches diagonal
      #pragma unroll
      for (int r = 0; r < 4; r++) if (s0 + lg * 4 + r > t_g) sA[r] = -1e30f;
    }
    if (!skipB && s0 + 31 > tb){             // tileB touches diagonal
      #pragma unroll
      for (int r = 0; r < 4; r++) if (s0 + 16 + lg * 4 + r > t_g) sB[r] = -1e30f;
    }

    // per-row (t=lr) tile max, replicated over lg
    float tm = fmaxf(fmaxf(fmaxf(sA[0], sA[1]), fmaxf(sA[2], sA[3])),
                     fmaxf(fmaxf(sB[0], sB[1]), fmaxf(sB[2], sB[3])));
    tm = fmaxf(tm, __shfl_xor(tm, 16, 64));
    tm = fmaxf(tm, __shfl_xor(tm, 32, 64));
    float mn = fmaxf(m, tm);
    float fac = __expf(m - mn);
    l *= fac;
    // rescale O: O rows are t=lg*4+r -> fetch fac per row via shuffle
    {
      float f0 = __shfl(fac, lg * 4 + 0, 64);
      float f1 = __shfl(fac, lg * 4 + 1, 64);
      float f2 = __shfl(fac, lg * 4 + 2, 64);
      float f3 = __shfl(fac, lg * 4 + 3, 64);
      o[0] *= f0; o[1] *= f1; o[2] *= f2; o[3] *= f3;
    }
    // P = exp(S - mn)
    f32x4 pA, pB;
    #pragma unroll
    for (int r = 0; r < 4; r++){ pA[r] = __expf(sA[r] - mn); pB[r] = __expf(sB[r] - mn); }
    float ls = pA[0] + pA[1] + pA[2] + pA[3] + pB[0] + pB[1] + pB[2] + pB[3];
    ls += __shfl_xor(ls, 16, 64);
    ls += __shfl_xor(ls, 32, 64);
    l += ls;
    m = mn;

    // redistribute P^T -> PV A-frag: lane needs P[t=lr][s=lg*8+i]
    u32 a0 = pack2(pA[0], pA[1]), a1 = pack2(pA[2], pA[3]);
    u32 b0 = pack2(pB[0], pB[1]), b1 = pack2(pB[2], pB[3]);
    int src0 = ((2 * lg) & 3) * 16 + lr;
    int src1 = src0 + 16;
    u32 A0 = __shfl((int)a0, src0, 64), A1 = __shfl((int)a1, src0, 64);
    u32 A2 = __shfl((int)a0, src1, 64), A3 = __shfl((int)a1, src1, 64);
    u32 B0 = __shfl((int)b0, src0, 64), B1 = __shfl((int)b1, src0, 64);
    u32 B2 = __shfl((int)b0, src1, 64), B3 = __shfl((int)b1, src1, 64);
    union { u32 u[4]; short8v v; } pu;
    if (lg < 2){ pu.u[0] = A0; pu.u[1] = A1; pu.u[2] = A2; pu.u[3] = A3; }
    else       { pu.u[0] = B0; pu.u[1] = B1; pu.u[2] = B2; pu.u[3] = B3; }

    // V frag (B-operand): lane holds V[s=lg*8+i][d=lr], d<8 real
    short8v vf = {0,0,0,0,0,0,0,0};
    if (lr < 8) vf = *(const short8v*)(vt16 + ((size_t)bh * 8 + lr) * TT + s0 + lg * 8);

    o = __builtin_amdgcn_mfma_f32_16x16x32_bf16(pu.v, vf, o, 0, 0, 0);
  }

  // epilogue: divide rows by l, store O[t=lg*4+r][d=lr<8]
  float linv = 1.f / l;                 // per t=lr, replicated over lg
  float i0 = __shfl(linv, lg * 4 + 0, 64);
  float i1 = __shfl(linv, lg * 4 + 1, 64);
  float i2 = __shfl(linv, lg * 4 + 2, 64);
  float i3 = __shfl(linv, lg * 4 + 3, 64);
  if (lr < 8){
    int b = bh >> 3, head = bh & 7;
    float* op = att + ((size_t)b * TT + tb) * 64 + head * 8 + lr;
    op[(lg * 4 + 0) * 64] = o[0] * i0;
    op[(lg * 4 + 1) * 64] = o[1] * i1;
    op[(lg * 4 + 2) * 64] = o[2] * i2;
    op[(lg * 4 + 3) * 64] = o[3] * i3;
  }
}

// ---------------- h += LN(attn_out) ----------------
__global__ void k_lnres(const float* __restrict__ src, const float* __restrict__ g,
                        const float* __restrict__ bb, float* __restrict__ h){
  int tid = threadIdx.x;
  int row = blockIdx.x * 4 + (tid >> 6);
  int lane = tid & 63;
  float x = src[row * 64 + lane];
  float s = x, sq = x * x;
  for (int msk = 32; msk; msk >>= 1){
    s += __shfl_xor(s, msk, 64);
    sq += __shfl_xor(sq, msk, 64);
  }
  float mu = s * (1.f / 64);
  float var = sq * (1.f / 64) - mu * mu;
  float rstd = rsqrtf(fmaxf(var, 0.f) + 1e-5f);
  h[row * 64 + lane] += (x - mu) * rstd * g[lane] + bb[lane];
}

// ---------------- h += relu(LN2(h)@W1+b1)@W2 + b2 ----------------
__global__ void k_ffn(float* __restrict__ h, const float* __restrict__ g, const float* __restrict__ bb,
                      const float* __restrict__ w1, const float* __restrict__ b1,
                      const float* __restrict__ w2, const float* __restrict__ b2){
  __shared__ float z[8][64];
  __shared__ float a[8][256];
  int tid = threadIdx.x;
  int row0 = blockIdx.x * 8;
  {
    int rr = tid >> 5, cp = tid & 31;
    int c0 = cp * 2;
    const float* hp = h + (row0 + rr) * 64;
    float x0 = hp[c0], x1 = hp[c0 + 1];
    float s = x0 + x1, sq = x0 * x0 + x1 * x1;
    for (int msk = 16; msk; msk >>= 1){
      s += __shfl_xor(s, msk, 64);
      sq += __shfl_xor(sq, msk, 64);
    }
    float mu = s * (1.f / 64);
    float var = sq * (1.f / 64) - mu * mu;
    float rstd = rsqrtf(fmaxf(var, 0.f) + 1e-5f);
    z[rr][c0]     = (x0 - mu) * rstd * g[c0] + bb[c0];
    z[rr][c0 + 1] = (x1 - mu) * rstd * g[c0 + 1] + bb[c0 + 1];
  }
  __syncthreads();
  {
    int j = tid;
    float acc[8];
    float bj = b1[j];
    #pragma unroll
    for (int r = 0; r < 8; r++) acc[r] = bj;
    for (int c = 0; c < 64; c++){
      float w = w1[c * 256 + j];
      #pragma unroll
      for (int r = 0; r < 8; r++) acc[r] += z[r][c] * w;
    }
    #pragma unroll
    for (int r = 0; r < 8; r++) a[r][j] = fmaxf(acc[r], 0.f);
  }
  __syncthreads();
  #pragma unroll
  for (int half = 0; half < 2; half++){
    int oi = tid + half * 256;
    int r = oi >> 6, c = oi & 63;
    float acc = b2[c];
    for (int k = 0; k < 256; k++) acc += a[r][k] * w2[k * 64 + c];
    h[(row0 + r) * 64 + c] += acc;
  }
}

// ---------------- h -> bf16 ----------------
__global__ void k_h2b(const float* __restrict__ h, u16* __restrict__ hb){
  int i = blockIdx.x * 256 + threadIdx.x;
  hb[i] = f2b(h[i]);
}

// ---------------- logits = hb @ Wout + bout (MFMA), fused softmax partials ----------------
__global__ void __launch_bounds__(256) k_logits(const u16* __restrict__ hb, const u16* __restrict__ wt,
                                                const float* __restrict__ bout, float* __restrict__ logits,
                                                float2* __restrict__ part){
  int tid = threadIdx.x;
  int wave = tid >> 6, lane = tid & 63;
  int lr = lane & 15, lg = lane >> 4;
  int row0 = blockIdx.y * 64;
  int colw = blockIdx.x * 256 + wave * 64;

  short8v af[4][2];
  #pragma unroll
  for (int mi = 0; mi < 4; mi++)
    #pragma unroll
    for (int kk = 0; kk < 2; kk++)
      af[mi][kk] = *(const short8v*)(hb + (row0 + mi * 16 + lr) * 64 + kk * 32 + lg * 8);

  short8v bf[4][2];
  #pragma unroll
  for (int nf = 0; nf < 4; nf++){
    int col = colw + nf * 16 + lr;
    #pragma unroll
    for (int kk = 0; kk < 2; kk++)
      bf[nf][kk] = *(const short8v*)(wt + (size_t)col * 64 + kk * 32 + lg * 8);
  }

  f32x4 acc[4][4];
  #pragma unroll
  for (int mi = 0; mi < 4; mi++)
    #pragma unroll
    for (int nf = 0; nf < 4; nf++)
      acc[mi][nf] = (f32x4){0.f, 0.f, 0.f, 0.f};

  #pragma unroll
  for (int mi = 0; mi < 4; mi++){
    #pragma unroll
    for (int nf = 0; nf < 4; nf++){
      acc[mi][nf] = __builtin_amdgcn_mfma_f32_16x16x32_bf16(af[mi][0], bf[nf][0], acc[mi][nf], 0, 0, 0);
      acc[mi][nf] = __builtin_amdgcn_mfma_f32_16x16x32_bf16(af[mi][1], bf[nf][1], acc[mi][nf], 0, 0, 0);
    }
  }

  float bo[4];
  #pragma unroll
  for (int nf = 0; nf < 4; nf++) bo[nf] = bout[colw + nf * 16 + lr];

  #pragma unroll
  for (int mi = 0; mi < 4; mi++){
    #pragma unroll
    for (int nf = 0; nf < 4; nf++){
      int colg = colw + nf * 16 + lr;
      #pragma unroll
      for (int r = 0; r < 4; r++){
        int rowg = row0 + mi * 16 + lg * 4 + r;
        logits[(size_t)rowg * VV + colg] = acc[mi][nf][r] + bo[nf];
      }
    }
  }

  __shared__ float2 wml[4][64];
  #pragma unroll
  for (int mi = 0; mi < 4; mi++){
    #pragma unroll
    for (int r = 0; r < 4; r++){
      float v0 = acc[mi][0][r] + bo[0], v1 = acc[mi][1][r] + bo[1];
      float v2 = acc[mi][2][r] + bo[2], v3 = acc[mi][3][r] + bo[3];
      float mx = fmaxf(fmaxf(v0, v1), fmaxf(v2, v3));
      for (int msk = 1; msk < 16; msk <<= 1) mx = fmaxf(mx, __shfl_xor(mx, msk, 64));
      float sume = __expf(v0 - mx) + __expf(v1 - mx) + __expf(v2 - mx) + __expf(v3 - mx);
      for (int msk = 1; msk < 16; msk <<= 1) sume += __shfl_xor(sume, msk, 64);
      if (lr == 0) wml[wave][mi * 16 + lg * 4 + r] = make_float2(mx, sume);
    }
  }
  __syncthreads();
  if (tid < 64){
    float M = -1e30f;
    #pragma unroll
    for (int w = 0; w < 4; w++) M = fmaxf(M, wml[w][tid].x);
    float L = 0.f;
    #pragma unroll
    for (int w = 0; w < 4; w++){
      float2 p = wml[w][tid];
      L += p.y * __expf(p.x - M);
    }
    part[(size_t)blockIdx.x * NR + row0 + tid] = make_float2(M, L);
  }
}

// ---------------- loss reduction ----------------
__global__ void k_loss(const float2* __restrict__ part, const float* __restrict__ logits,
                       const int* __restrict__ tgt, float* __restrict__ lpart){
  int row = blockIdx.x * 256 + threadIdx.x;
  float M = -1e30f;
  for (int j = 0; j < NCB; j++) M = fmaxf(M, part[(size_t)j * NR + row].x);
  float L = 0.f;
  for (int j = 0; j < NCB; j++){
    float2 p = part[(size_t)j * NR + row];
    L += p.y * __expf(p.x - M);
  }
  float lse = M + __logf(L);
  float tl = logits[(size_t)row * VV + tgt[row]];
  float nll = lse - tl;
  __shared__ float red[4];
  for (int msk = 32; msk; msk >>= 1) nll += __shfl_xor(nll, msk, 64);
  if ((threadIdx.x & 63) == 0) red[threadIdx.x >> 6] = nll;
  __syncthreads();
  if (threadIdx.x == 0) lpart[blockIdx.x] = red[0] + red[1] + red[2] + red[3];
}
__global__ void k_loss2(const float* __restrict__ lpart, float* __restrict__ out){
  if (threadIdx.x == 0 && blockIdx.x == 0){
    float s = 0.f;
    for (int i = 0; i < 32; i++) s += lpart[i];
    out[NLOGIT] = s * (1.f / NR);
  }
}

extern "C" void kernel_launch(void* const* d_in, const int* in_sizes, int n_in,
                              void* d_out, int out_size, void* d_ws, size_t ws_size,
                              hipStream_t stream){
  (void)in_sizes; (void)n_in; (void)out_size; (void)ws_size;
  const int* x = (const int*)d_in[0];
  const int* targets = (const int*)d_in[1];
  float* out = (float*)d_out;

  static const int WN[18] = {2048000, 65536, 16384, 256, 16384, 256, 16384, 256,
                             256, 256, 256, 256, 65536, 1024, 65536, 256, 2048000, 32000};
  char* ws = (char*)d_ws;
  size_t off = 0;
  auto alloc = [&](size_t bytes) -> void* {
    void* p = ws + off;
    off += (bytes + 255) & ~(size_t)255;
    return p;
  };
  int* flag = (int*)alloc(256);
  float* wf[18];
  for (int i = 0; i < 18; i++) wf[i] = (float*)alloc((size_t)WN[i] * 4);
  float* h     = (float*)alloc((size_t)NR * 64 * 4);
  float* att_o = (float*)alloc((size_t)NR * 64 * 4);
  u16* q16     = (u16*)alloc((size_t)NR * 64 * 2);
  u16* kp16    = (u16*)alloc((size_t)NR * 64 * 2);
  u16* vt16    = (u16*)alloc((size_t)NR * 64 * 2);
  u16* hb      = (u16*)alloc((size_t)NR * 64 * 2);
  u16* wt16    = (u16*)alloc((size_t)2048000 * 2);
  float2* part = (float2*)alloc((size_t)NCB * NR * 8);
  float* lpart = (float*)alloc(32 * 4);

  hipLaunchKernelGGL(k_probe, dim3(1), dim3(64), 0, stream, d_in[10], flag);
  ConvArgs ca;
  int blk = 0;
  for (int i = 0; i < 18; i++){
    ca.src[i] = d_in[2 + i];
    ca.dst[i] = wf[i];
    ca.n[i] = WN[i];
    ca.blkoff[i] = blk;
    blk += (WN[i] + 1023) / 1024;
  }
  ca.blkoff[18] = blk;
  ca.flag = flag;
  ca.wt16 = wt16;
  hipLaunchKernelGGL(k_convert, dim3(blk), dim3(256), 0, stream, ca);

  hipLaunchKernelGGL(k_embed, dim3(2048), dim3(256), 0, stream, x, wf[0], wf[1], h);

  for (int l = 0; l < NLAY; l++){
    hipLaunchKernelGGL(k_qkv, dim3(2048), dim3(256), 0, stream, h,
                       wf[2] + l * 4096, wf[3] + l * 64,
                       wf[4] + l * 4096, wf[5] + l * 64,
                       wf[6] + l * 4096, wf[7] + l * 64,
                       q16, kp16, vt16);
    hipLaunchKernelGGL(k_attn, dim3(64, 64), dim3(64), 0, stream, q16, kp16, vt16, att_o);
    hipLaunchKernelGGL(k_lnres, dim3(2048), dim3(256), 0, stream, att_o,
                       wf[8] + l * 64, wf[9] + l * 64, h);
    hipLaunchKernelGGL(k_ffn, dim3(1024), dim3(256), 0, stream, h,
                       wf[10] + l * 64, wf[11] + l * 64,
                       wf[12] + l * 16384, wf[13] + l * 256,
                       wf[14] + l * 16384, wf[15] + l * 64);
  }

  hipLaunchKernelGGL(k_h2b, dim3(2048), dim3(256), 0, stream, h, hb);
  hipLaunchKernelGGL(k_logits, dim3(NCB, 128), dim3(256), 0, stream, hb, wt16, wf[17], out, part);
  hipLaunchKernelGGL(k_loss, dim3(32), dim3(256), 0, stream, part, out, targets, lpart);
  hipLaunchKernelGGL(k_loss2, dim3(1), dim3(64), 0, stream, lpart, out);
}

// Round 3
// 735.190 us; speedup vs baseline: 1.1224x; 1.0773x over previous
//
#include <hip/hip_runtime.h>
#include <hip/hip_bf16.h>
#include <math.h>

#define BB 8
#define TT 1024
#define CC 64
#define HH 8
#define DH 8
#define NLAY 4
#define VV 32000
#define FF 256
#define NR (BB*TT)                 // 8192
#define NLOGIT 262144000           // NR*VV
#define NCB 125                    // 32000/256 col-chunks

typedef unsigned short u16;
typedef unsigned int u32;
typedef __attribute__((ext_vector_type(8))) short short8v;
typedef __attribute__((ext_vector_type(4))) float f32x4;

__device__ __forceinline__ float b2f(u16 u){
  union { float f; u32 i; } c; c.i = ((u32)u) << 16; return c.f;
}
__device__ __forceinline__ u16 f2b(float f){
  union { float f; u32 i; } c; c.f = f;
  u32 x = c.i;
  return (u16)((x + 0x7FFF + ((x >> 16) & 1)) >> 16);
}
__device__ __forceinline__ u32 pack2(float lo, float hi){
  return (u32)f2b(lo) | ((u32)f2b(hi) << 16);
}
// dtype probe via 64-lane ballot on ln1_g (~N(1,0.02)): bf16 -> all 64 high
// bytes 0x3F; f32 -> only odd u16s (~32). Threshold 48.
__device__ __forceinline__ int probe_bf16(const void* ln1g){
  const u16* lp = (const u16*)ln1g;
  unsigned long long m = __ballot((lp[threadIdx.x & 63] >> 8) == 0x3F);
  return (__popcll(m) > 48) ? 1 : 0;
}

// ---------------- convert float inputs -> f32 ws ----------------
struct ConvArgs {
  const void* src[18];
  float* dst[18];
  int n[18];
  int blkoff[19];
};
__global__ void k_convert(ConvArgs a, const void* ln1g){
  int isb = probe_bf16(ln1g);
  int bid = blockIdx.x;
  int t = 0;
  while (bid >= a.blkoff[t + 1]) t++;
  int base = (bid - a.blkoff[t]) * 1024 + threadIdx.x;
  const u16* s16 = (const u16*)a.src[t];
  const float* s32 = (const float*)a.src[t];
  float* d = a.dst[t];
  int n = a.n[t];
  #pragma unroll
  for (int e = 0; e < 4; e++){
    int i = base + e * 256;
    if (i < n) d[i] = isb ? b2f(s16[i]) : s32[i];
  }
}

// ---------------- Wout [64][32000] -> Wout^T bf16 [32000][64], coalesced ----------------
__global__ void __launch_bounds__(256) k_trans(const void* __restrict__ wsrc, const void* __restrict__ ln1g,
                                               u16* __restrict__ wt){
  __shared__ float ws_[64][65];
  int tid = threadIdx.x;
  int isb = probe_bf16(ln1g);
  int v0 = blockIdx.x * 64;
  const u16* s16 = (const u16*)wsrc;
  const float* s32 = (const float*)wsrc;
  int vl = tid & 63;
  #pragma unroll
  for (int kk = 0; kk < 16; kk++){
    int k = kk * 4 + (tid >> 6);
    size_t idx = (size_t)k * VV + v0 + vl;
    ws_[vl][k] = isb ? b2f(s16[idx]) : s32[idx];
  }
  __syncthreads();
  #pragma unroll
  for (int pass = 0; pass < 16; pass++){
    int v2 = pass * 4 + (tid >> 6);
    int k = tid & 63;
    wt[(size_t)(v0 + v2) * 64 + k] = f2b(ws_[v2][k]);
  }
}

// ---------------- embedding ----------------
__global__ void k_embed(const int* __restrict__ x, const float* __restrict__ tok,
                        const float* __restrict__ pos, float* __restrict__ h){
  int i = blockIdx.x * 256 + threadIdx.x;
  int r = i >> 6, c = i & 63;
  int t = r & (TT - 1);
  h[i] = tok[x[r] * 64 + c] + pos[t * 64 + c];
}

// ---------------- qkv projection -> bf16 (q scaled, k permuted, v transposed) ----------------
__global__ void k_qkv(const float* __restrict__ h,
                      const float* __restrict__ wq, const float* __restrict__ bq,
                      const float* __restrict__ wk, const float* __restrict__ bk,
                      const float* __restrict__ wv, const float* __restrict__ bv,
                      u16* __restrict__ q16, u16* __restrict__ kp16, u16* __restrict__ vt16){
  __shared__ float hs[4][64];
  int tid = threadIdx.x;
  int row0 = blockIdx.x * 4;
  hs[tid >> 6][tid & 63] = h[row0 * 64 + tid];
  __syncthreads();
  int rr = tid >> 6, o = tid & 63;
  int head = o >> 3, d = o & 7;
  int row = row0 + rr;
  int b = row >> 10, t = row & (TT - 1);
  float aq = bq[head * 8 + d], ak = bk[head * 8 + d], av = bv[head * 8 + d];
  #pragma unroll
  for (int c = 0; c < 64; c++){
    float hv = hs[rr][c];
    aq += hv * wq[(head * 64 + c) * 8 + d];
    ak += hv * wk[(head * 64 + c) * 8 + d];
    av += hv * wv[(head * 64 + c) * 8 + d];
  }
  int bh = b * HH + head;
  q16[((size_t)bh * TT + t) * 8 + d] = f2b(aq * 0.35355339059327378f);  // fold 1/sqrt(8)
  int i = t * 8 + d;                                  // faithful reshape(B,H,D,T)
  kp16[((size_t)bh * TT + (i & 1023)) * 8 + (i >> 10)] = f2b(ak);
  vt16[((size_t)bh * 8 + d) * TT + t] = f2b(av);
}

// ---------------- MFMA causal attention + LN1 + residual, 8 waves = 8 heads ----------------
__global__ void __launch_bounds__(512) k_attn2(const u16* __restrict__ q16, const u16* __restrict__ kp16,
                                               const u16* __restrict__ vt16, const float* __restrict__ g,
                                               const float* __restrict__ be, float* __restrict__ h){
  __shared__ float ot[16][64];
  int tid = threadIdx.x;
  int w = tid >> 6;                  // head
  int lane = tid & 63;
  int lr = lane & 15, lg = lane >> 4;
  int b = blockIdx.y;
  int bh = b * HH + w;
  int tb = blockIdx.x * 16;
  int t_g = tb + lr;

  short8v qf = {0,0,0,0,0,0,0,0};
  if (lg == 0) qf = *(const short8v*)(q16 + ((size_t)bh * TT + tb + lr) * 8);

  float m = -1e30f, l = 0.f;
  f32x4 o = {0.f, 0.f, 0.f, 0.f};
  int nchunk = (tb >> 5) + 1;

  for (int c = 0; c < nchunk; c++){
    int s0 = c * 32;
    bool skipB = (s0 + 16 > tb + 15);
    short8v kA = {0,0,0,0,0,0,0,0}, kB = {0,0,0,0,0,0,0,0};
    if (lg == 0){
      kA = *(const short8v*)(kp16 + ((size_t)bh * TT + s0 + lr) * 8);
      if (!skipB) kB = *(const short8v*)(kp16 + ((size_t)bh * TT + s0 + 16 + lr) * 8);
    }
    f32x4 sA = __builtin_amdgcn_mfma_f32_16x16x32_bf16(kA, qf, (f32x4){0.f,0.f,0.f,0.f}, 0, 0, 0);
    f32x4 sB;
    if (!skipB)
      sB = __builtin_amdgcn_mfma_f32_16x16x32_bf16(kB, qf, (f32x4){0.f,0.f,0.f,0.f}, 0, 0, 0);
    else
      sB = (f32x4){-1e30f, -1e30f, -1e30f, -1e30f};

    if (s0 + 15 > tb){
      #pragma unroll
      for (int r = 0; r < 4; r++) if (s0 + lg * 4 + r > t_g) sA[r] = -1e30f;
    }
    if (!skipB && s0 + 31 > tb){
      #pragma unroll
      for (int r = 0; r < 4; r++) if (s0 + 16 + lg * 4 + r > t_g) sB[r] = -1e30f;
    }

    float tm = fmaxf(fmaxf(fmaxf(sA[0], sA[1]), fmaxf(sA[2], sA[3])),
                     fmaxf(fmaxf(sB[0], sB[1]), fmaxf(sB[2], sB[3])));
    tm = fmaxf(tm, __shfl_xor(tm, 16, 64));
    tm = fmaxf(tm, __shfl_xor(tm, 32, 64));
    float mn = fmaxf(m, tm);
    float fac = __expf(m - mn);
    l *= fac;
    {
      float f0 = __shfl(fac, lg * 4 + 0, 64);
      float f1 = __shfl(fac, lg * 4 + 1, 64);
      float f2 = __shfl(fac, lg * 4 + 2, 64);
      float f3 = __shfl(fac, lg * 4 + 3, 64);
      o[0] *= f0; o[1] *= f1; o[2] *= f2; o[3] *= f3;
    }
    f32x4 pA, pB;
    #pragma unroll
    for (int r = 0; r < 4; r++){ pA[r] = __expf(sA[r] - mn); pB[r] = __expf(sB[r] - mn); }
    float ls = pA[0] + pA[1] + pA[2] + pA[3] + pB[0] + pB[1] + pB[2] + pB[3];
    ls += __shfl_xor(ls, 16, 64);
    ls += __shfl_xor(ls, 32, 64);
    l += ls;
    m = mn;

    u32 a0 = pack2(pA[0], pA[1]), a1 = pack2(pA[2], pA[3]);
    u32 b0 = pack2(pB[0], pB[1]), b1 = pack2(pB[2], pB[3]);
    int src0 = ((2 * lg) & 3) * 16 + lr;
    int src1 = src0 + 16;
    u32 A0 = __shfl((int)a0, src0, 64), A1 = __shfl((int)a1, src0, 64);
    u32 A2 = __shfl((int)a0, src1, 64), A3 = __shfl((int)a1, src1, 64);
    u32 B0 = __shfl((int)b0, src0, 64), B1 = __shfl((int)b1, src0, 64);
    u32 B2 = __shfl((int)b0, src1, 64), B3 = __shfl((int)b1, src1, 64);
    union { u32 u[4]; short8v v; } pu;
    if (lg < 2){ pu.u[0] = A0; pu.u[1] = A1; pu.u[2] = A2; pu.u[3] = A3; }
    else       { pu.u[0] = B0; pu.u[1] = B1; pu.u[2] = B2; pu.u[3] = B3; }

    short8v vf = {0,0,0,0,0,0,0,0};
    if (lr < 8) vf = *(const short8v*)(vt16 + ((size_t)bh * 8 + lr) * TT + s0 + lg * 8);

    o = __builtin_amdgcn_mfma_f32_16x16x32_bf16(pu.v, vf, o, 0, 0, 0);
  }

  float linv = 1.f / l;
  float i0 = __shfl(linv, lg * 4 + 0, 64);
  float i1 = __shfl(linv, lg * 4 + 1, 64);
  float i2 = __shfl(linv, lg * 4 + 2, 64);
  float i3 = __shfl(linv, lg * 4 + 3, 64);
  if (lr < 8){
    ot[lg * 4 + 0][w * 8 + lr] = o[0] * i0;
    ot[lg * 4 + 1][w * 8 + lr] = o[1] * i1;
    ot[lg * 4 + 2][w * 8 + lr] = o[2] * i2;
    ot[lg * 4 + 3][w * 8 + lr] = o[3] * i3;
  }
  __syncthreads();

  // LN over channels + residual into h, 16 rows, 8 rows per pass
  #pragma unroll
  for (int pass = 0; pass < 2; pass++){
    int rl = (tid >> 6) + pass * 8;
    float x = ot[rl][lane];
    float s = x, sq = x * x;
    for (int msk = 32; msk; msk >>= 1){
      s += __shfl_xor(s, msk, 64);
      sq += __shfl_xor(sq, msk, 64);
    }
    float mu = s * (1.f / 64);
    float var = sq * (1.f / 64) - mu * mu;
    float rstd = rsqrtf(fmaxf(var, 0.f) + 1e-5f);
    h[((size_t)b * TT + tb + rl) * 64 + lane] += (x - mu) * rstd * g[lane] + be[lane];
  }
}

// ---------------- h += relu(LN2(h)@W1+b1)@W2 + b2 (+optional bf16 emit) ----------------
__global__ void k_ffn(float* __restrict__ h, const float* __restrict__ g, const float* __restrict__ bb,
                      const float* __restrict__ w1, const float* __restrict__ b1,
                      const float* __restrict__ w2, const float* __restrict__ b2,
                      u16* __restrict__ hbo, int last){
  __shared__ float z[8][64];
  __shared__ float a[8][256];
  int tid = threadIdx.x;
  int row0 = blockIdx.x * 8;
  {
    int rr = tid >> 5, cp = tid & 31;
    int c0 = cp * 2;
    const float* hp = h + (row0 + rr) * 64;
    float x0 = hp[c0], x1 = hp[c0 + 1];
    float s = x0 + x1, sq = x0 * x0 + x1 * x1;
    for (int msk = 16; msk; msk >>= 1){
      s += __shfl_xor(s, msk, 64);
      sq += __shfl_xor(sq, msk, 64);
    }
    float mu = s * (1.f / 64);
    float var = sq * (1.f / 64) - mu * mu;
    float rstd = rsqrtf(fmaxf(var, 0.f) + 1e-5f);
    z[rr][c0]     = (x0 - mu) * rstd * g[c0] + bb[c0];
    z[rr][c0 + 1] = (x1 - mu) * rstd * g[c0 + 1] + bb[c0 + 1];
  }
  __syncthreads();
  {
    int j = tid;
    float acc[8];
    float bj = b1[j];
    #pragma unroll
    for (int r = 0; r < 8; r++) acc[r] = bj;
    for (int c = 0; c < 64; c++){
      float w = w1[c * 256 + j];
      #pragma unroll
      for (int r = 0; r < 8; r++) acc[r] += z[r][c] * w;
    }
    #pragma unroll
    for (int r = 0; r < 8; r++) a[r][j] = fmaxf(acc[r], 0.f);
  }
  __syncthreads();
  #pragma unroll
  for (int half = 0; half < 2; half++){
    int oi = tid + half * 256;
    int r = oi >> 6, c = oi & 63;
    float acc = b2[c];
    for (int k = 0; k < 256; k++) acc += a[r][k] * w2[k * 64 + c];
    int gi = (row0 + r) * 64 + c;
    float nh = h[gi] + acc;
    h[gi] = nh;
    if (last) hbo[gi] = f2b(nh);
  }
}

// ---------------- logits^T-frag GEMM: mfma(W,h) -> f32x4 col-contiguous NT stores ----------------
__global__ void __launch_bounds__(256) k_logits(const u16* __restrict__ hb, const u16* __restrict__ wt,
                                                const float* __restrict__ bout, float* __restrict__ logits,
                                                float2* __restrict__ part){
  int tid = threadIdx.x;
  int wave = tid >> 6, lane = tid & 63;
  int lr = lane & 15, lg = lane >> 4;
  int row0 = blockIdx.x * 64;            // x fastest: consecutive blocks share W-tile
  int cb = blockIdx.y;
  int colw = cb * 256 + wave * 64;

  short8v hf[4][2];
  #pragma unroll
  for (int ri = 0; ri < 4; ri++)
    #pragma unroll
    for (int kk = 0; kk < 2; kk++)
      hf[ri][kk] = *(const short8v*)(hb + (row0 + ri * 16 + lr) * 64 + kk * 32 + lg * 8);

  short8v wfr[4][2];
  #pragma unroll
  for (int vi = 0; vi < 4; vi++)
    #pragma unroll
    for (int kk = 0; kk < 2; kk++)
      wfr[vi][kk] = *(const short8v*)(wt + (size_t)(colw + vi * 16 + lr) * 64 + kk * 32 + lg * 8);

  f32x4 acc[4][4];
  #pragma unroll
  for (int ri = 0; ri < 4; ri++)
    #pragma unroll
    for (int vi = 0; vi < 4; vi++)
      acc[ri][vi] = (f32x4){0.f, 0.f, 0.f, 0.f};

  #pragma unroll
  for (int ri = 0; ri < 4; ri++){
    #pragma unroll
    for (int vi = 0; vi < 4; vi++){
      acc[ri][vi] = __builtin_amdgcn_mfma_f32_16x16x32_bf16(wfr[vi][0], hf[ri][0], acc[ri][vi], 0, 0, 0);
      acc[ri][vi] = __builtin_amdgcn_mfma_f32_16x16x32_bf16(wfr[vi][1], hf[ri][1], acc[ri][vi], 0, 0, 0);
    }
  }

  f32x4 bo[4];
  #pragma unroll
  for (int vi = 0; vi < 4; vi++)
    bo[vi] = *(const f32x4*)(bout + colw + vi * 16 + lg * 4);

  __shared__ float2 wml[4][64];
  #pragma unroll
  for (int ri = 0; ri < 4; ri++){
    f32x4 vals[4];
    #pragma unroll
    for (int vi = 0; vi < 4; vi++){
      vals[vi] = acc[ri][vi] + bo[vi];
      __builtin_nontemporal_store(vals[vi],
        (f32x4*)(logits + (size_t)(row0 + ri * 16 + lr) * VV + colw + vi * 16 + lg * 4));
    }
    float mx = -1e30f;
    #pragma unroll
    for (int vi = 0; vi < 4; vi++)
      #pragma unroll
      for (int r = 0; r < 4; r++) mx = fmaxf(mx, vals[vi][r]);
    mx = fmaxf(mx, __shfl_xor(mx, 16, 64));
    mx = fmaxf(mx, __shfl_xor(mx, 32, 64));
    float sume = 0.f;
    #pragma unroll
    for (int vi = 0; vi < 4; vi++)
      #pragma unroll
      for (int r = 0; r < 4; r++) sume += __expf(vals[vi][r] - mx);
    sume += __shfl_xor(sume, 16, 64);
    sume += __shfl_xor(sume, 32, 64);
    if (lg == 0) wml[wave][ri * 16 + lr] = make_float2(mx, sume);
  }
  __syncthreads();
  if (tid < 64){
    float M = -1e30f;
    #pragma unroll
    for (int w = 0; w < 4; w++) M = fmaxf(M, wml[w][tid].x);
    float L = 0.f;
    #pragma unroll
    for (int w = 0; w < 4; w++){
      float2 p = wml[w][tid];
      L += p.y * __expf(p.x - M);
    }
    part[(size_t)cb * NR + row0 + tid] = make_float2(M, L);
  }
}

// ---------------- loss reduction ----------------
__global__ void k_loss(const float2* __restrict__ part, const float* __restrict__ logits,
                       const int* __restrict__ tgt, float* __restrict__ lpart){
  int row = blockIdx.x * 64 + (threadIdx.x & 63);
  float M = -1e30f;
  for (int j = 0; j < NCB; j++) M = fmaxf(M, part[(size_t)j * NR + row].x);
  float L = 0.f;
  for (int j = 0; j < NCB; j++){
    float2 p = part[(size_t)j * NR + row];
    L += p.y * __expf(p.x - M);
  }
  float lse = M + __logf(L);
  float tl = logits[(size_t)row * VV + tgt[row]];
  float nll = lse - tl;
  for (int msk = 32; msk; msk >>= 1) nll += __shfl_xor(nll, msk, 64);
  if ((threadIdx.x & 63) == 0) lpart[blockIdx.x] = nll;
}
__global__ void k_loss2(const float* __restrict__ lpart, float* __restrict__ out){
  int lane = threadIdx.x & 63;
  float s = lpart[lane] + lpart[lane + 64];
  for (int msk = 32; msk; msk >>= 1) s += __shfl_xor(s, msk, 64);
  if (lane == 0) out[NLOGIT] = s * (1.f / NR);
}

extern "C" void kernel_launch(void* const* d_in, const int* in_sizes, int n_in,
                              void* d_out, int out_size, void* d_ws, size_t ws_size,
                              hipStream_t stream){
  (void)in_sizes; (void)n_in; (void)out_size; (void)ws_size;
  const int* x = (const int*)d_in[0];
  const int* targets = (const int*)d_in[1];
  float* out = (float*)d_out;

  // Wout (idx 16) handled by k_trans; 0 blocks here.
  static const int WN[18] = {2048000, 65536, 16384, 256, 16384, 256, 16384, 256,
                             256, 256, 256, 256, 65536, 1024, 65536, 256, 0, 32000};
  char* ws = (char*)d_ws;
  size_t off = 0;
  auto alloc = [&](size_t bytes) -> void* {
    void* p = ws + off;
    off += (bytes + 255) & ~(size_t)255;
    return p;
  };
  float* wf[18];
  for (int i = 0; i < 18; i++) wf[i] = (float*)alloc((size_t)(WN[i] ? WN[i] : 1) * 4);
  float* h     = (float*)alloc((size_t)NR * 64 * 4);
  u16* q16     = (u16*)alloc((size_t)NR * 64 * 2);
  u16* kp16    = (u16*)alloc((size_t)NR * 64 * 2);
  u16* vt16    = (u16*)alloc((size_t)NR * 64 * 2);
  u16* hb      = (u16*)alloc((size_t)NR * 64 * 2);
  u16* wt16    = (u16*)alloc((size_t)2048000 * 2);
  float2* part = (float2*)alloc((size_t)NCB * NR * 8);
  float* lpart = (float*)alloc(128 * 4);

  ConvArgs ca;
  int blk = 0;
  for (int i = 0; i < 18; i++){
    ca.src[i] = d_in[2 + i];
    ca.dst[i] = wf[i];
    ca.n[i] = WN[i];
    ca.blkoff[i] = blk;
    blk += (WN[i] + 1023) / 1024;
  }
  ca.blkoff[18] = blk;
  hipLaunchKernelGGL(k_convert, dim3(blk), dim3(256), 0, stream, ca, d_in[10]);
  hipLaunchKernelGGL(k_trans, dim3(500), dim3(256), 0, stream, d_in[18], d_in[10], wt16);
  hipLaunchKernelGGL(k_embed, dim3(2048), dim3(256), 0, stream, x, wf[0], wf[1], h);

  for (int l = 0; l < NLAY; l++){
    hipLaunchKernelGGL(k_qkv, dim3(2048), dim3(256), 0, stream, h,
                       wf[2] + l * 4096, wf[3] + l * 64,
                       wf[4] + l * 4096, wf[5] + l * 64,
                       wf[6] + l * 4096, wf[7] + l * 64,
                       q16, kp16, vt16);
    hipLaunchKernelGGL(k_attn2, dim3(64, 8), dim3(512), 0, stream, q16, kp16, vt16,
                       wf[8] + l * 64, wf[9] + l * 64, h);
    hipLaunchKernelGGL(k_ffn, dim3(1024), dim3(256), 0, stream, h,
                       wf[10] + l * 64, wf[11] + l * 64,
                       wf[12] + l * 16384, wf[13] + l * 256,
                       wf[14] + l * 16384, wf[15] + l * 64,
                       hb, (l == NLAY - 1) ? 1 : 0);
  }

  hipLaunchKernelGGL(k_logits, dim3(128, NCB), dim3(256), 0, stream, hb, wt16, wf[17], out, part);
  hipLaunchKernelGGL(k_loss, dim3(128), dim3(64), 0, stream, part, out, targets, lpart);
  hipLaunchKernelGGL(k_loss2, dim3(1), dim3(64), 0, stream, lpart, out);
}